// Round 13
// baseline (2781.756 us; speedup 1.0000x reference)
//
#include <hip/hip_runtime.h>
#include <hip/hip_bf16.h>
#include <math.h>

#define LL 4096
#define LP3 4072
#define NB 100              // 25 taps x 4 vocab
#define SC 0.088388347648318447f   // 1/sqrt(128)

// Conv stack is LINEAR (no nonlinearity), vocab = 4:
// x3[l] = B3 + sum_{u<25} V3[u][tok[l+u]]  (exact composition).
// score[l] = base + sum_u S[u][tok[l+u]];  out = Wv.(B3 + (V3^T A)/esum) + bv.

// ---- kV123: whole table chain in ONE kernel. grid 5 x 1024.
// blocks 0..3: v = blk; V1[9] -> V2[17] (LDS) -> V3[25] (global).
// block 4: B2 -> B3 bias chain.
__global__ __launch_bounds__(1024)
void kV123(const float* __restrict__ w1, const float* __restrict__ emb,
           const float* __restrict__ wr, const float* __restrict__ br,
           const float* __restrict__ b1, float* __restrict__ V3,
           float* __restrict__ B3){
  __shared__ float V1L[9][128];
  __shared__ float V2L[17][128];
  __shared__ float part[8][128];
  __shared__ float bb2[128];
  int tid = threadIdx.x, c = tid & 127, g = tid >> 7;
  const float* w2 = wr;                  // layer-1 conv weights [128][128][9]
  const float* w3 = wr + 147456;         // layer-2 conv weights

  if (blockIdx.x == 4){                  // bias chain, cin split 8-way
    float acc = 0.f;
    int cin0 = g*16;
    for (int cin=cin0; cin<cin0+16; ++cin){
      const float* wc = w2 + c*1152 + cin*9;
      float ws = 0.f;
      #pragma unroll
      for (int s=0;s<9;s++) ws += wc[s];
      acc += ws*b1[cin];
    }
    part[g][c] = acc;
    __syncthreads();
    if (g==0){
      float s2 = br[c];
      #pragma unroll
      for (int k=0;k<8;k++) s2 += part[k][c];
      bb2[c] = s2;
    }
    __syncthreads();
    acc = 0.f;
    for (int cin=cin0; cin<cin0+16; ++cin){
      const float* wc = w3 + c*1152 + cin*9;
      float ws = 0.f;
      #pragma unroll
      for (int s=0;s<9;s++) ws += wc[s];
      acc += ws*bb2[cin];
    }
    part[g][c] = acc;
    __syncthreads();
    if (g==0){
      float s3 = br[128 + c];
      #pragma unroll
      for (int k=0;k<8;k++) s3 += part[k][c];
      B3[c] = s3;
    }
    return;
  }

  const int v = blockIdx.x;
  __shared__ float ev[128];
  if (tid < 128) ev[tid] = emb[v*128 + tid];
  __syncthreads();
  // V1[t] = W1[.,.,t] . emb[v]
  for (int t = g; t < 9; t += 8){
    const float* w = w1 + c*1152 + t;
    float acc = 0.f;
    #pragma unroll 8
    for (int cin=0; cin<128; ++cin) acc += w[cin*9]*ev[cin];
    V1L[t][c] = acc;
  }
  __syncthreads();
  // V2[t2] = sum_s W2[s].V1[t2-s]
  for (int t2 = g; t2 < 17; t2 += 8){
    float acc = 0.f;
    for (int cin=0; cin<128; ++cin){
      const float* wc = w2 + c*1152 + cin*9;
      float x = 0.f;
      #pragma unroll
      for (int s=0;s<9;s++){
        int t1 = t2 - s;
        float vv = (t1>=0 && t1<9) ? V1L[t1][cin] : 0.f;
        x += wc[s]*vv;
      }
      acc += x;
    }
    V2L[t2][c] = acc;
  }
  __syncthreads();
  // V3[u] = sum_s W3[s].V2[u-s]  -> global
  for (int u = g; u < 25; u += 8){
    float acc = 0.f;
    for (int cin=0; cin<128; ++cin){
      const float* wc = w3 + c*1152 + cin*9;
      float x = 0.f;
      #pragma unroll
      for (int s=0;s<9;s++){
        int t2 = u - s;
        float vv = (t2>=0 && t2<17) ? V2L[t2][cin] : 0.f;
        x += wc[s]*vv;
      }
      acc += x;
    }
    V3[(u*4+v)*128 + c] = acc;
  }
}

// ---- kBATCH: everything per-batch in one block. grid 128 x 1024.
// counts -> mean -> q -> qk -> S -> scores/exp -> esum -> A -> out.
__global__ __launch_bounds__(1024)
void kBATCH(const int* __restrict__ tokens, const float* __restrict__ V3,
            const float* __restrict__ B3, const float* __restrict__ wq,
            const float* __restrict__ bq, const float* __restrict__ wk,
            const float* __restrict__ bk, const float* __restrict__ wv,
            const float* __restrict__ bv, float* __restrict__ out){
  __shared__ int   tkl[LL];              // 16 KB
  __shared__ float ebuf[LP3];            // 16.3 KB
  __shared__ float S[NB], Al[NB], cnt[NB];
  __shared__ float mv[128], qv[128], qks[128], b3s[128], bks[128], tvec[128];
  __shared__ float part[8][128];
  __shared__ float red[16][4];
  __shared__ float wsum[16];
  __shared__ float sbase, sesum;
  int b = blockIdx.x, tid = threadIdx.x;
  int c = tid & 127, p = tid >> 7;
  const int* tg = tokens + b*LL;
  for (int i = tid; i < LL; i += 1024) tkl[i] = tg[i];
  if (tid < 128){ b3s[tid] = B3[tid]; bks[tid] = bk[tid]; }
  if (tid < NB) Al[tid] = 0.f;
  __syncthreads();
  // full-4096 token counts
  {
    float c0=0,c1=0,c2=0,c3=0;
    #pragma unroll
    for (int k=0;k<4;k++){
      int t = tkl[k*1024 + tid];
      c0 += (t==0); c1 += (t==1); c2 += (t==2); c3 += (t==3);
    }
    for (int d=1; d<64; d<<=1){
      c0 += __shfl_xor(c0,d); c1 += __shfl_xor(c1,d);
      c2 += __shfl_xor(c2,d); c3 += __shfl_xor(c3,d);
    }
    if ((tid&63)==0){
      int w = tid>>6;
      red[w][0]=c0; red[w][1]=c1; red[w][2]=c2; red[w][3]=c3;
    }
  }
  __syncthreads();
  if (tid < 25){
    float n0=0,n1=0,n2=0,n3=0;
    #pragma unroll
    for (int w=0; w<16; w++){ n0+=red[w][0]; n1+=red[w][1]; n2+=red[w][2]; n3+=red[w][3]; }
    for (int pp=0; pp<tid; pp++){              // prefix [0,u)
      int t = tkl[pp];
      n0 -= (t==0); n1 -= (t==1); n2 -= (t==2); n3 -= (t==3);
    }
    for (int pp=tid+LP3; pp<LL; pp++){         // suffix [u+LP3, 4096)
      int t = tkl[pp];
      n0 -= (t==0); n1 -= (t==1); n2 -= (t==2); n3 -= (t==3);
    }
    cnt[tid*4+0]=n0; cnt[tid*4+1]=n1; cnt[tid*4+2]=n2; cnt[tid*4+3]=n3;
  }
  __syncthreads();
  // mean: mv = B3 + (sum_j V3[j]*cnt[j]) / LP3   (j split 8-way over 100)
  {
    int j0 = (p<4) ? p*13 : 52+(p-4)*12;
    int jl = (p<4) ? 13 : 12;
    float acc = 0.f;
    for (int j=j0; j<j0+jl; j++) acc += V3[j*128+c]*cnt[j];
    part[p][c] = acc;
  }
  __syncthreads();
  if (p==0){
    float s = 0.f;
    #pragma unroll
    for (int k=0;k<8;k++) s += part[k][c];
    mv[c] = b3s[c] + s*(1.0f/LP3);
  }
  __syncthreads();
  // q = Wq.mv + bq (j split 8x16)
  {
    float acc = 0.f;
    int j0 = p*16;
    #pragma unroll 8
    for (int j=j0; j<j0+16; j++) acc += wq[c*128+j]*mv[j];
    part[p][c] = acc;
  }
  __syncthreads();
  if (p==0){
    float s = bq[c];
    #pragma unroll
    for (int k=0;k<8;k++) s += part[k][c];
    qv[c] = s;
  }
  __syncthreads();
  // qk = SC * Wk^T q
  {
    float acc = 0.f;
    int d0 = p*16;
    #pragma unroll 8
    for (int d=d0; d<d0+16; d++) acc += qv[d]*wk[d*128+c];
    part[p][c] = acc;
  }
  __syncthreads();
  if (p==0){
    float s = 0.f;
    #pragma unroll
    for (int k=0;k<8;k++) s += part[k][c];
    qks[c] = s*SC;
  }
  __syncthreads();
  // S[j] = qk . V3[j] ; base = SC*q.bk + qk.B3
  {
    float acc = 0.f;
    if (c < NB){
      int d0 = p*16;
      #pragma unroll 8
      for (int d=d0; d<d0+16; d++) acc += qks[d]*V3[c*128+d];
    }
    part[p][c] = acc;
  }
  __syncthreads();
  if (p==0 && c < NB){
    float s = 0.f;
    #pragma unroll
    for (int k=0;k<8;k++) s += part[k][c];
    S[c] = s;
  }
  if (p==1){  // base reduce on wave pair (threads 128..255 hold c=0..127)
    float tb = qv[c]*bks[c]*SC + qks[c]*b3s[c];
    for (int d=1; d<64; d<<=1) tb += __shfl_xor(tb, d);
    if ((c&63)==0) wsum[c>>6] = tb;
  }
  __syncthreads();
  if (tid==0) sbase = wsum[0] + wsum[1];
  __syncthreads();
  // scores + exp (|score| O(1): no max needed) + esum
  {
    float es = 0.f;
    float base = sbase;
    for (int l = tid; l < LP3; l += 1024){
      float sc = base;
      #pragma unroll
      for (int u=0;u<25;u++) sc += S[u*4 + tkl[l+u]];
      float e = __expf(sc);
      ebuf[l] = e;
      es += e;
    }
    for (int d=1; d<64; d<<=1) es += __shfl_xor(es, d);
    if ((tid&63)==0) wsum[tid>>6] = es;
  }
  __syncthreads();
  if (tid==0){
    float s = 0.f;
    #pragma unroll
    for (int k=0;k<16;k++) s += wsum[k];
    sesum = s;
  }
  // A-correlation: 1000 threads = 25 u x 40 chunks of 102
  if (tid < 1000){
    int u = tid/40, ch = tid%40;
    int i0 = ch*102, i1 = i0+102; if (i1 > LP3) i1 = LP3;
    float a0=0.f,a1=0.f,a2=0.f,a3=0.f;
    #pragma unroll 2
    for (int i=i0; i<i1; ++i){
      float ev = ebuf[i];
      int t = tkl[i+u];
      a0 += (t==0)?ev:0.f; a1 += (t==1)?ev:0.f;
      a2 += (t==2)?ev:0.f; a3 += (t==3)?ev:0.f;
    }
    atomicAdd(&Al[u*4+0], a0); atomicAdd(&Al[u*4+1], a1);
    atomicAdd(&Al[u*4+2], a2); atomicAdd(&Al[u*4+3], a3);
  }
  __syncthreads();
  // tvec = B3 + (sum_j V3[j]*Al[j]) / esum
  {
    int j0 = (p<4) ? p*13 : 52+(p-4)*12;
    int jl = (p<4) ? 13 : 12;
    float acc = 0.f;
    for (int j=j0; j<j0+jl; j++) acc += V3[j*128+c]*Al[j];
    part[p][c] = acc;
  }
  __syncthreads();
  if (p==0){
    float s = 0.f;
    #pragma unroll
    for (int k=0;k<8;k++) s += part[k][c];
    tvec[c] = b3s[c] + s/sesum;
  }
  __syncthreads();
  // out = Wv.tvec + bv
  {
    float acc = 0.f;
    int j0 = p*16;
    #pragma unroll 8
    for (int j=j0; j<j0+16; j++) acc += wv[c*128+j]*tvec[j];
    part[p][c] = acc;
  }
  __syncthreads();
  if (p==0){
    float s = bv[c];
    #pragma unroll
    for (int k=0;k<8;k++) s += part[k][c];
    out[b*128+c] = s;
  }
}

extern "C" void kernel_launch(void* const* d_in, const int* in_sizes, int n_in,
                              void* d_out, int out_size, void* d_ws, size_t ws_size,
                              hipStream_t stream){
  const int*   tokens = (const int*)d_in[0];
  const float* emb    = (const float*)d_in[1];
  const float* w1     = (const float*)d_in[2];
  const float* b1     = (const float*)d_in[3];
  const float* wr     = (const float*)d_in[4];
  const float* br     = (const float*)d_in[5];
  const float* wqw    = (const float*)d_in[6];
  const float* wqb    = (const float*)d_in[7];
  const float* wkw    = (const float*)d_in[8];
  const float* wkb    = (const float*)d_in[9];
  const float* wvw    = (const float*)d_in[10];
  const float* wvb    = (const float*)d_in[11];
  float* out = (float*)d_out;

  const size_t NEED = 65536;
  if (ws_size < NEED){
    hipMemsetAsync(d_out, 0, (size_t)out_size*4, stream);
    return;
  }
  float* ws = (float*)d_ws;
  float* V3 = ws;                    // 12800 floats
  float* B3 = ws + 12800;            //   128 floats

  kV123 <<<5,   1024, 0, stream>>>(w1, emb, wr, br, b1, V3, B3);
  kBATCH<<<128, 1024, 0, stream>>>(tokens, V3, B3, wqw, wqb, wkw, wkb,
                                   wvw, wvb, out);
}